// Round 1
// baseline (12753.838 us; speedup 1.0000x reference)
//
#include <hip/hip_runtime.h>
#include <math.h>

#define BN_EPS 1e-3f

__device__ __forceinline__ float hsig(float x) {
    return fminf(fmaxf(0.2f * x + 0.5f, 0.f), 1.f);
}

// Fused gate GEMM for one timestep of one ConvLSTM layer.
// g[b,l,n] = bias[n] + sum_k sum_ci xt[b,l+k-1,ci]*Wx[k,ci,n]
//                    + sum_k sum_f  h[b,l+k-1,f] *Wh[k,f,n]
// grid: (N4/64, L/64, B), block: 256 threads. Tile 64(l) x 64(n), TK=16.
__global__ __launch_bounds__(256)
void gate_gemm(const float* __restrict__ xt,  // input seq, base at timestep t
               long xt_batch_stride,          // T*L*Cin
               int Cin,
               const float* __restrict__ Wx,  // [3, Cin, N4]
               const float* __restrict__ h,   // [B, L, F]
               int F,
               const float* __restrict__ Wh,  // [3, F, N4]
               const float* __restrict__ bias,// [N4]
               float* __restrict__ g,         // [B, L, N4]
               int N4, int L)
{
    __shared__ float As[66][17];                      // +1 pad: avoid 4-way bank conflict
    __shared__ __align__(16) float Ws[3][16][64];

    const int n0 = blockIdx.x * 64;
    const int l0 = blockIdx.y * 64;
    const int b  = blockIdx.z;
    const int tid = threadIdx.x;
    const int tn = tid & 15;         // 16 col-groups of 4
    const int tm = tid >> 4;         // 16 row-groups of 4

    float acc[4][4];
#pragma unroll
    for (int i = 0; i < 4; ++i)
#pragma unroll
        for (int j = 0; j < 4; ++j) acc[i][j] = 0.f;

    for (int src = 0; src < 2; ++src) {
        const float* A = (src == 0) ? (xt + (long)b * xt_batch_stride)
                                    : (h + (long)b * L * F);
        const float* W = (src == 0) ? Wx : Wh;
        const int C = (src == 0) ? Cin : F;

        for (int c0 = 0; c0 < C; c0 += 16) {
            // stage A rows l0-1 .. l0+64 (66 rows) x 16 channels, zero-padded
            for (int idx = tid; idx < 66 * 16; idx += 256) {
                int r = idx >> 4, c = idx & 15;
                int l = l0 - 1 + r;
                int ch = c0 + c;
                float v = 0.f;
                if (l >= 0 && l < L && ch < C) v = A[(long)l * C + ch];
                As[r][c] = v;
            }
            // stage W [3][16][64]
            for (int idx = tid; idx < 3 * 16 * 64; idx += 256) {
                int k = idx >> 10;
                int rem = idx & 1023;
                int c = rem >> 6, n = rem & 63;
                int ch = c0 + c;
                float v = 0.f;
                if (ch < C) v = W[((long)k * C + ch) * N4 + n0 + n];
                Ws[k][c][n] = v;
            }
            __syncthreads();

#pragma unroll
            for (int k = 0; k < 3; ++k) {
#pragma unroll 4
                for (int c = 0; c < 16; ++c) {
                    float a0 = As[tm * 4 + 0 + k][c];
                    float a1 = As[tm * 4 + 1 + k][c];
                    float a2 = As[tm * 4 + 2 + k][c];
                    float a3 = As[tm * 4 + 3 + k][c];
                    const float4 w4 = *(const float4*)&Ws[k][c][tn * 4];
                    acc[0][0] += a0 * w4.x; acc[0][1] += a0 * w4.y;
                    acc[0][2] += a0 * w4.z; acc[0][3] += a0 * w4.w;
                    acc[1][0] += a1 * w4.x; acc[1][1] += a1 * w4.y;
                    acc[1][2] += a1 * w4.z; acc[1][3] += a1 * w4.w;
                    acc[2][0] += a2 * w4.x; acc[2][1] += a2 * w4.y;
                    acc[2][2] += a2 * w4.z; acc[2][3] += a2 * w4.w;
                    acc[3][0] += a3 * w4.x; acc[3][1] += a3 * w4.y;
                    acc[3][2] += a3 * w4.z; acc[3][3] += a3 * w4.w;
                }
            }
            __syncthreads();
        }
    }

    const float4 bb = *(const float4*)&bias[n0 + tn * 4];
#pragma unroll
    for (int i = 0; i < 4; ++i) {
        int l = l0 + tm * 4 + i;
        float4 o;
        o.x = acc[i][0] + bb.x;
        o.y = acc[i][1] + bb.y;
        o.z = acc[i][2] + bb.z;
        o.w = acc[i][3] + bb.w;
        *(float4*)&g[((long)b * L + l) * N4 + n0 + tn * 4] = o;
    }
}

// Elementwise gate combine + state update + fused BN write of h.
// one thread per (b,l,f); grid = B*L*F/256.
__global__ __launch_bounds__(256)
void gate_update(const float* __restrict__ g,   // [B, L, 4F]
                 float* __restrict__ c_state,   // [B, L, F]
                 float* __restrict__ h_state,   // [B, L, F]
                 float* __restrict__ out,       // bn(h) destination (may be null)
                 long out_batch_stride,
                 const float* __restrict__ bn_g, const float* __restrict__ bn_b,
                 const float* __restrict__ bn_m, const float* __restrict__ bn_v,
                 int F, int L)
{
    int idx = blockIdx.x * 256 + threadIdx.x;   // over B*L*F
    int f = idx % F;
    int bl = idx / F;
    int b = bl / L;

    const float* gb = g + (long)bl * 4 * F;
    float gi = gb[f];
    float gf = gb[F + f];
    float gc = gb[2 * F + f];
    float go = gb[3 * F + f];

    float c = c_state[idx];
    float cn = hsig(gf) * c + hsig(gi) * fmaxf(gc, 0.f);
    float hn = hsig(go) * fmaxf(cn, 0.f);
    c_state[idx] = cn;
    h_state[idx] = hn;

    if (out) {
        float bnv = (hn - bn_m[f]) * rsqrtf(bn_v[f] + BN_EPS) * bn_g[f] + bn_b[f];
        out[(long)b * out_batch_stride + (idx - (long)b * L * F)] = bnv;
    }
}

// Dense + ReLU: out[m,n] = relu(bias[n] + sum_k A[m,k]*Wt[k,n])
// grid: (N/256, M); block 256. K and N must be multiples of 256.
__global__ __launch_bounds__(256)
void dense_relu(const float* __restrict__ A,   // [M, K]
                const float* __restrict__ Wt,  // [K, N]
                const float* __restrict__ bias,
                float* __restrict__ out, int K, int N)
{
    __shared__ float As[256];
    int n = blockIdx.x * 256 + threadIdx.x;
    int m = blockIdx.y;
    float acc = 0.f;
    for (int k0 = 0; k0 < K; k0 += 256) {
        __syncthreads();
        As[threadIdx.x] = A[(long)m * K + k0 + threadIdx.x];
        __syncthreads();
#pragma unroll 8
        for (int kk = 0; kk < 256; ++kk)
            acc += As[kk] * Wt[(long)(k0 + kk) * N + n];
    }
    out[(long)m * N + n] = fmaxf(acc + bias[n], 0.f);
}

// Final dense (512 -> 5) + softmax. grid = 32 (batch), block = 64 (one wave).
__global__ __launch_bounds__(64)
void dense_softmax(const float* __restrict__ A,  // [32, 512]
                   const float* __restrict__ W,  // [512, 5]
                   const float* __restrict__ bias,
                   float* __restrict__ out)      // [32, 5]
{
    int b = blockIdx.x;
    int tid = threadIdx.x;
    __shared__ float logits[5];

    float part[5] = {0.f, 0.f, 0.f, 0.f, 0.f};
    for (int k = tid; k < 512; k += 64) {
        float a = A[b * 512 + k];
#pragma unroll
        for (int j = 0; j < 5; ++j) part[j] += a * W[k * 5 + j];
    }
#pragma unroll
    for (int j = 0; j < 5; ++j) {
        float v = part[j];
        for (int off = 32; off; off >>= 1) v += __shfl_down(v, off);
        if (tid == 0) logits[j] = v + bias[j];
    }
    __syncthreads();
    if (tid == 0) {
        float mx = logits[0];
        for (int j = 1; j < 5; ++j) mx = fmaxf(mx, logits[j]);
        float s = 0.f, e[5];
        for (int j = 0; j < 5; ++j) { e[j] = expf(logits[j] - mx); s += e[j]; }
        for (int j = 0; j < 5; ++j) out[b * 5 + j] = e[j] / s;
    }
}

extern "C" void kernel_launch(void* const* d_in, const int* in_sizes, int n_in,
                              void* d_out, int out_size, void* d_ws, size_t ws_size,
                              hipStream_t stream)
{
    const int B = 32, T = 32, L = 128;
    const int F1 = 64, F2 = 128, F3 = 256;

    const float* x   = (const float*)d_in[0];   // [B, T, L]
    const float* Wx1 = (const float*)d_in[1];   // [3, 1, 256]
    const float* Wh1 = (const float*)d_in[2];   // [3, 64, 256]
    const float* b1  = (const float*)d_in[3];
    const float* Wx2 = (const float*)d_in[4];   // [3, 64, 512]
    const float* Wh2 = (const float*)d_in[5];   // [3, 128, 512]
    const float* b2  = (const float*)d_in[6];
    const float* Wx3 = (const float*)d_in[7];   // [3, 128, 1024]
    const float* Wh3 = (const float*)d_in[8];   // [3, 256, 1024]
    const float* b3  = (const float*)d_in[9];
    const float* g1  = (const float*)d_in[10];
    const float* be1 = (const float*)d_in[11];
    const float* m1  = (const float*)d_in[12];
    const float* v1  = (const float*)d_in[13];
    const float* g2  = (const float*)d_in[14];
    const float* be2 = (const float*)d_in[15];
    const float* m2  = (const float*)d_in[16];
    const float* v2  = (const float*)d_in[17];
    const float* g3  = (const float*)d_in[18];
    const float* be3 = (const float*)d_in[19];
    const float* m3  = (const float*)d_in[20];
    const float* v3  = (const float*)d_in[21];
    const float* D1  = (const float*)d_in[22];  // [32768, 1024]
    const float* db1 = (const float*)d_in[23];
    const float* D2  = (const float*)d_in[24];  // [1024, 512]
    const float* db2 = (const float*)d_in[25];
    const float* D3  = (const float*)d_in[26];  // [512, 5]
    const float* db3 = (const float*)d_in[27];

    float* ws = (float*)d_ws;
    size_t off = 0;
    float* h1seq = ws + off; off += (size_t)B * T * L * F1;   // 8.39M
    float* h2seq = ws + off; off += (size_t)B * T * L * F2;   // 16.78M
    float* gbuf  = ws + off; off += (size_t)B * L * 4 * F3;   // 4.19M
    float* hst   = ws + off; off += (size_t)B * L * F3;       // 1.05M
    float* cst   = ws + off; off += (size_t)B * L * F3;
    float* h3bn  = ws + off; off += (size_t)B * L * F3;
    float* a1    = ws + off; off += (size_t)B * 1024;
    float* a2    = ws + off; off += (size_t)B * 512;
    (void)ws_size; (void)in_sizes; (void)n_in; (void)out_size;

    // ---------------- Layer 1: Cin=1, F=64 ----------------
    hipMemsetAsync(hst, 0, (size_t)B * L * F1 * sizeof(float), stream);
    hipMemsetAsync(cst, 0, (size_t)B * L * F1 * sizeof(float), stream);
    for (int t = 0; t < T; ++t) {
        dim3 grid(4 * F1 / 64, L / 64, B);
        gate_gemm<<<grid, 256, 0, stream>>>(x + (long)t * L, (long)T * L, 1, Wx1,
                                            hst, F1, Wh1, b1, gbuf, 4 * F1, L);
        gate_update<<<(B * L * F1) / 256, 256, 0, stream>>>(
            gbuf, cst, hst, h1seq + (long)t * L * F1, (long)T * L * F1,
            g1, be1, m1, v1, F1, L);
    }

    // ---------------- Layer 2: Cin=64, F=128 ----------------
    hipMemsetAsync(hst, 0, (size_t)B * L * F2 * sizeof(float), stream);
    hipMemsetAsync(cst, 0, (size_t)B * L * F2 * sizeof(float), stream);
    for (int t = 0; t < T; ++t) {
        dim3 grid(4 * F2 / 64, L / 64, B);
        gate_gemm<<<grid, 256, 0, stream>>>(h1seq + (long)t * L * F1, (long)T * L * F1,
                                            F1, Wx2, hst, F2, Wh2, b2, gbuf, 4 * F2, L);
        gate_update<<<(B * L * F2) / 256, 256, 0, stream>>>(
            gbuf, cst, hst, h2seq + (long)t * L * F2, (long)T * L * F2,
            g2, be2, m2, v2, F2, L);
    }

    // ---------------- Layer 3: Cin=128, F=256, last h only ----------------
    hipMemsetAsync(hst, 0, (size_t)B * L * F3 * sizeof(float), stream);
    hipMemsetAsync(cst, 0, (size_t)B * L * F3 * sizeof(float), stream);
    for (int t = 0; t < T; ++t) {
        dim3 grid(4 * F3 / 64, L / 64, B);
        gate_gemm<<<grid, 256, 0, stream>>>(h2seq + (long)t * L * F2, (long)T * L * F2,
                                            F2, Wx3, hst, F3, Wh3, b3, gbuf, 4 * F3, L);
        gate_update<<<(B * L * F3) / 256, 256, 0, stream>>>(
            gbuf, cst, hst, (t == T - 1) ? h3bn : nullptr, (long)L * F3,
            g3, be3, m3, v3, F3, L);
    }

    // ---------------- Dense head ----------------
    dense_relu<<<dim3(1024 / 256, B), 256, 0, stream>>>(h3bn, D1, db1, a1, L * F3, 1024);
    dense_relu<<<dim3(512 / 256, B), 256, 0, stream>>>(a1, D2, db2, a2, 1024, 512);
    dense_softmax<<<B, 64, 0, stream>>>(a2, D3, db3, (float*)d_out);
}